// Round 3
// baseline (415.609 us; speedup 1.0000x reference)
//
#include <hip/hip_runtime.h>

#define EMB 128
#define W1LD 532  // PRED_IN
#define KP 160    // padded K for MFMA (138 -> 160)
#define ST 264    // LDS row stride (u16) in node path

typedef unsigned long long u64;
typedef unsigned short u16;
typedef __attribute__((ext_vector_type(8))) short short8;
typedef __attribute__((ext_vector_type(4))) float f32x4;
typedef __attribute__((ext_vector_type(4))) unsigned uint32x4;

__device__ __forceinline__ u16 f2bf(float x) {
    unsigned u = __float_as_uint(x);
    unsigned r = (u + 0x7fffu + ((u >> 16) & 1u)) >> 16;
    return (u16)r;
}
__device__ __forceinline__ float bf2f(u16 u) { return __uint_as_float((unsigned)u << 16); }
__device__ __forceinline__ float bf2f_lo(unsigned u) { return __uint_as_float(u << 16); }
__device__ __forceinline__ float bf2f_hi(unsigned u) { return __uint_as_float(u & 0xffff0000u); }

// round-1 mean, unpacked inline from packed accumulator
__device__ __forceinline__ float2 unpack1_mean(u64 a) {
    float c = (float)(unsigned)(a >> 42);
    float inv = (1.0f / 8192.0f) / fmaxf(c, 1.0f);
    float2 v;
    v.x = (float)(unsigned)(a & 0x1FFFFFull) * inv;
    v.y = (float)(unsigned)((a >> 21) & 0x1FFFFFull) * inv;
    return v;
}

// ---------------------------------------------------------------------------
// k_bin: per-bucket edge counts (bucket = h / bsz, 8 buckets).
// LDS-aggregated; 8 global atomics per block (25K total -> negligible).
// ---------------------------------------------------------------------------
__global__ __launch_bounds__(256) void k_bin(
    const int* __restrict__ h_id, unsigned* __restrict__ bcnt,
    int E, int bsz)
{
    __shared__ unsigned lh[8];
    const int t = threadIdx.x;
    if (t < 8) lh[t] = 0;
    __syncthreads();
    int e = blockIdx.x * 256 + t;
    if (e < E) atomicAdd(&lh[h_id[e] / bsz], 1u);
    __syncthreads();
    if (t < 8) atomicAdd(&bcnt[t], lh[t]);
}

// k_off: exclusive scan of 8 bucket counts -> boff; init running cursors.
__global__ __launch_bounds__(64) void k_off(
    const unsigned* __restrict__ bcnt,
    unsigned* __restrict__ boff, unsigned* __restrict__ bcur)
{
    if (threadIdx.x == 0) {
        unsigned s = 0;
#pragma unroll
        for (int i = 0; i < 8; i++) { boff[i] = s; bcur[i] = s; s += bcnt[i]; }
    }
}

// ---------------------------------------------------------------------------
// K1: scatter1 (blocks 0..ns-1) || prep (blocks ns..ns+KP+NREL) ||
//     perm-scatter (last ns blocks, only when bucketed path active).
// scatter pack: [x*2^13:21b][y*2^13:21b][count:22b], device atomics.
// perm record: h[0:17) | t[17:34) | r[34:43) | e[43:64)
// ---------------------------------------------------------------------------
__global__ __launch_bounds__(256) void k1_scatter1_prep(
    const int* __restrict__ h_id, const int* __restrict__ r_id,
    const int* __restrict__ t_id,
    const float* __restrict__ topic,
    u64* __restrict__ acc_t, u64* __restrict__ acc_h,
    const float* __restrict__ W1, const float* __restrict__ q,
    const float* __restrict__ rel, const float* __restrict__ b1,
    u16* __restrict__ WBF, float* __restrict__ qWb, u16* __restrict__ Rbf,
    u64* __restrict__ perm, unsigned* __restrict__ bcur,
    int E, int ns, int NREL, int bsz)
{
    const int bid = blockIdx.x, t = threadIdx.x;
    if (bid < ns) {
        int e = bid * 256 + t;
        if (e >= E) return;
        int h = h_id[e], tt = t_id[e];
        float2 th = *(const float2*)(topic + 2 * h);
        float2 tv = *(const float2*)(topic + 2 * tt);
        u64 p1 = (u64)__float2uint_rn(th.x * 8192.0f)
               | ((u64)__float2uint_rn(th.y * 8192.0f) << 21)
               | (1ull << 42);
        u64 p3 = (u64)__float2uint_rn(tv.x * 8192.0f)
               | ((u64)__float2uint_rn(tv.y * 8192.0f) << 21)
               | (1ull << 42);
        atomicAdd(&acc_t[tt], p1);
        atomicAdd(&acc_h[h], p3);
        return;
    }
    const int pb = bid - ns;
    if (pb < KP) {
        int k = pb, n = t;
        float v = 0.0f;
        if (k < 138) {
            v = (n < 128) ? W1[(size_t)n * W1LD + 128 + k]
                          : W1[(size_t)(n - 128) * W1LD + 394 + k];
        }
        int kstep = k >> 5, quad = (k >> 3) & 3, j = k & 7;
        WBF[(((size_t)(kstep * 4 + quad) * 256 + n) << 3) + j] = f2bf(v);
        return;
    }
    if (pb < KP + 1 + NREL) {
        int b = pb - KP;   // 0 -> qWb ; 1..NREL -> relation b-1
        __shared__ float v[EMB];
        if (t < EMB) v[t] = (b == 0) ? q[t] : rel[(size_t)(b - 1) * EMB + t];
        __syncthreads();
        if (t < EMB) {
            const float* w = W1 + (size_t)t * W1LD + (b == 0 ? 0 : 266);
            float s = 0.0f;
#pragma unroll
            for (int k = 0; k < EMB; k += 4) {
                float4 wv = *(const float4*)(w + k);
                s += wv.x * v[k] + wv.y * v[k + 1] + wv.z * v[k + 2] + wv.w * v[k + 3];
            }
            if (b == 0) qWb[t] = s + b1[t];
            else        Rbf[(size_t)(b - 1) * EMB + t] = f2bf(s);
        }
        return;
    }
    // ---------------- perm-scatter (bucketed k4 path) ----------------
    {
        const int pe = (pb - (KP + 1 + NREL)) * 256 + t;
        __shared__ unsigned lh[8], gb[8];
        if (t < 8) lh[t] = 0;
        __syncthreads();
        int b = 0, h = 0, r = 0, tt = 0;
        unsigned rank = 0;
        if (pe < E) {
            h = h_id[pe]; r = r_id[pe]; tt = t_id[pe];
            b = h / bsz;
            rank = atomicAdd(&lh[b], 1u);
        }
        __syncthreads();
        if (t < 8) gb[t] = atomicAdd(&bcur[t], lh[t]);
        __syncthreads();
        if (pe < E) {
            u64 rec = (u64)h | ((u64)tt << 17) | ((u64)r << 34) | ((u64)pe << 43);
            perm[gb[b] + rank] = rec;
        }
    }
}

// ---------------------------------------------------------------------------
// K2: interleaved  odd blocks -> scatter2 ; even blocks -> node MFMA GEMM.
// node computes A/B with ALL 8 dde tail dims zeroed (deferred to K3 fixup);
// it reads NO round-2 accumulators -> race-free vs concurrent scatter2.
// Round 2 pack: [x*2^20 : 32b][y*2^20 : 32b]
// ---------------------------------------------------------------------------
__global__ __launch_bounds__(256) void k2_scatter2_node(
    const int* __restrict__ h_id, const int* __restrict__ t_id,
    const u64* __restrict__ acc1_t, const u64* __restrict__ acc1_h,
    u64* __restrict__ acc2_t, u64* __restrict__ acc2_h,
    const float* __restrict__ ent, const float* __restrict__ nte,
    const float* __restrict__ topic,
    const u16* __restrict__ WBF, const float* __restrict__ qWb,
    u16* __restrict__ A, u16* __restrict__ B,
    int E, int ns, int NT, int N, int nn)
{
    __shared__ __align__(16) u16 lds[32 * ST];
    const int bid = blockIdx.x, t = threadIdx.x;
    const int half = bid >> 1;

    if (bid & 1) {
        // ---------------- scatter2 ----------------
        if (half >= ns) return;
        int e = half * 256 + t;
        if (e >= E) return;
        int h = h_id[e], tt = t_id[e];
        float2 v1 = unpack1_mean(acc1_t[h]);   // dde1[h]
        float2 v3 = unpack1_mean(acc1_h[tt]);  // dde3[t]
        const float sc = 1048576.0f;  // 2^20
        u64 p2 = (u64)__float2uint_rn(v1.x * sc)
               | ((u64)__float2uint_rn(v1.y * sc) << 32);
        u64 p4 = (u64)__float2uint_rn(v3.x * sc)
               | ((u64)__float2uint_rn(v3.y * sc) << 32);
        atomicAdd(&acc2_t[tt], p2);
        atomicAdd(&acc2_h[h], p4);
        return;
    }

    // ---------------- node GEMM (partial: no dde dims) ----------------
    if (half >= nn) return;
    const int lane = t & 63;
    const int w    = t >> 6;
    const int ln15 = lane & 15;
    const int quad = lane >> 4;
    const int m0   = (w & 1) * 16;
    const int n0   = (w >> 1) * 128;
    const int nblk = half * 32;

    {   // stage dense features as bf16: thread -> node m=t>>3, 16 k-elems
        int m  = t >> 3;
        int kq = (t & 7) << 4;
        int gn = nblk + m;
        const float* src = (gn < N) ? ((gn < NT) ? ent + (size_t)gn * EMB + kq
                                                 : nte + kq)
                                    : nte;
        u16 pk[16];
#pragma unroll
        for (int p = 0; p < 4; p++) {
            float4 v = (gn < N) ? *(const float4*)(src + 4 * p)
                                : make_float4(0.f, 0.f, 0.f, 0.f);
            pk[4 * p + 0] = f2bf(v.x); pk[4 * p + 1] = f2bf(v.y);
            pk[4 * p + 2] = f2bf(v.z); pk[4 * p + 3] = f2bf(v.w);
        }
        *(uint4*)&lds[m * ST + kq]     = *(uint4*)&pk[0];
        *(uint4*)&lds[m * ST + kq + 8] = *(uint4*)&pk[8];
    }
    // tail: topic only (k=128,129); k=130..159 zero (dde deferred to fixup)
    if (t < 32) {
        int gn = nblk + t;
        float2 tp = (gn < N) ? *(const float2*)(topic + 2 * gn)
                             : make_float2(0.f, 0.f);
        lds[t * ST + 128] = f2bf(tp.x);
        lds[t * ST + 129] = f2bf(tp.y);
#pragma unroll
        for (int z = 130; z < KP; z++) lds[t * ST + z] = 0;
    }
    __syncthreads();

    f32x4 acc[8];
#pragma unroll
    for (int i = 0; i < 8; i++) acc[i] = (f32x4){0.f, 0.f, 0.f, 0.f};

    const u16* wbbase = WBF + (((size_t)quad * 256 + n0 + ln15) << 3);
#pragma unroll
    for (int ks = 0; ks < 5; ks++) {
        short8 a = *(const short8*)&lds[(m0 + ln15) * ST + ks * 32 + quad * 8];
        const u16* wb = wbbase + ((size_t)ks * 4 * 256 * 8);
#pragma unroll
        for (int nt = 0; nt < 8; nt++) {
            short8 b = *(const short8*)(wb + (nt << 7));
            acc[nt] = __builtin_amdgcn_mfma_f32_16x16x32_bf16(a, b, acc[nt], 0, 0, 0);
        }
    }

    __syncthreads();   // all a-frag reads done before overwrite
#pragma unroll
    for (int nt = 0; nt < 8; nt++) {
        int c = n0 + nt * 16 + ln15;
        float qv = (n0 == 0) ? qWb[c] : 0.0f;
#pragma unroll
        for (int r = 0; r < 4; r++) {
            int row = m0 + quad * 4 + r;
            lds[row * ST + c] = f2bf(acc[nt][r] + qv);
        }
    }
    __syncthreads();
    {
        int m  = t >> 3;
        int c0 = (t & 7) * 32;
        int gn = nblk + m;
        if (gn < N) {
            uint4 v0 = *(uint4*)&lds[m * ST + c0];
            uint4 v1 = *(uint4*)&lds[m * ST + c0 + 8];
            uint4 v2 = *(uint4*)&lds[m * ST + c0 + 16];
            uint4 v3 = *(uint4*)&lds[m * ST + c0 + 24];
            u16* dst = (c0 < 128) ? (A + (size_t)gn * EMB + c0)
                                  : (B + (size_t)gn * EMB + (c0 - 128));
            ((uint4*)dst)[0] = v0;
            ((uint4*)dst)[1] = v1;
            ((uint4*)dst)[2] = v2;
            ((uint4*)dst)[3] = v3;
        }
    }
}

// ---------------------------------------------------------------------------
// K3 fixup: per-node rank-8 tail correction, A/B updated in place.
// ---------------------------------------------------------------------------
__global__ __launch_bounds__(256) void k3_fixup(
    const u64* __restrict__ acc1_t, const u64* __restrict__ acc1_h,
    const u64* __restrict__ acc2_t, const u64* __restrict__ acc2_h,
    const float* __restrict__ W1,
    u16* __restrict__ A, u16* __restrict__ B, int N)
{
    __shared__ float tvs[32][8];
    const int t = threadIdx.x;
    const int nblk = blockIdx.x * 32;

    if (t < 32) {
        int gn = nblk + t;
        float tv[8];
#pragma unroll
        for (int i = 0; i < 8; i++) tv[i] = 0.0f;
        if (gn < N) {
            u64 a1 = acc1_t[gn], b1v = acc1_h[gn];
            float2 d1 = unpack1_mean(a1);
            float2 d3 = unpack1_mean(b1v);
            const float is20 = 1.0f / 1048576.0f;
            float i1 = is20 / fmaxf((float)(unsigned)(a1 >> 42), 1.0f);
            float i2 = is20 / fmaxf((float)(unsigned)(b1v >> 42), 1.0f);
            u64 a2 = acc2_t[gn], b2v = acc2_h[gn];
            tv[0] = d1.x; tv[1] = d1.y;
            tv[2] = (float)(unsigned)(a2 & 0xFFFFFFFFull) * i1;   // dde2
            tv[3] = (float)(unsigned)(a2 >> 32) * i1;
            tv[4] = d3.x; tv[5] = d3.y;
            tv[6] = (float)(unsigned)(b2v & 0xFFFFFFFFull) * i2;  // dde4
            tv[7] = (float)(unsigned)(b2v >> 32) * i2;
        }
#pragma unroll
        for (int i = 0; i < 8; i++) tvs[t][i] = tv[i];
    }

    const int c = t & 127;
    const float* wp = W1 + (size_t)c * W1LD + ((t < 128) ? 258 : 524);
    float4 wv0 = *(const float4*)(wp);
    float4 wv1 = *(const float4*)(wp + 4);
    u16* dst = (t < 128) ? (A + c) : (B + c);
    __syncthreads();

#pragma unroll 4
    for (int m = 0; m < 32; m++) {
        int gn = nblk + m;
        if (gn >= N) break;
        const float* tv = tvs[m];
        float d = tv[0] * wv0.x + tv[1] * wv0.y + tv[2] * wv0.z + tv[3] * wv0.w
                + tv[4] * wv1.x + tv[5] * wv1.y + tv[6] * wv1.z + tv[7] * wv1.w;
        u16* p = dst + (size_t)gn * EMB;
        *p = f2bf(bf2f(*p) + d);
    }
}

// ---------------------------------------------------------------------------
// K4 (bucketed): bucket = blockIdx.x % 8 rides XCD round-robin dispatch, so
// each XCD's L2 holds one 3.2MB slice of A (h-range) -> A-gathers become
// L2 hits. B stays random (L3) and is loaded non-temporally so it doesn't
// evict the A slice. perm rec: h|t<<17|r<<34|e<<43.
// ---------------------------------------------------------------------------
__global__ __launch_bounds__(256) void edge_pred_bkt(
    const u64* __restrict__ perm,
    const unsigned* __restrict__ boff, const unsigned* __restrict__ bcnt,
    const u16* __restrict__ A, const u16* __restrict__ B,
    const u16* __restrict__ Rbf,
    const float* __restrict__ W2, const float* __restrict__ b2,
    float* __restrict__ out)
{
    const int bucket = blockIdx.x & 7;
    const int chunk  = blockIdx.x >> 3;
    const unsigned base = boff[bucket];
    const unsigned cnt  = bcnt[bucket];
    const unsigned i0   = (unsigned)chunk * 16u;
    if (i0 >= cnt) return;

    const int t    = threadIdx.x;
    const int lane = t & 63;
    const int g    = lane >> 4;
    const int k    = lane & 15;
    const int wv   = t >> 6;
    const unsigned idx = i0 + (unsigned)(wv * 4 + g);
    const bool valid = idx < cnt;

    const float4 w0 = *(const float4*)(W2 + k * 8);
    const float4 w1 = *(const float4*)(W2 + k * 8 + 4);

    float s = 0.0f;
    unsigned e = 0;
    if (valid) {
        u64 rec = perm[base + idx];
        unsigned h  = (unsigned)(rec & 0x1FFFFull);
        unsigned tt = (unsigned)((rec >> 17) & 0x1FFFFull);
        unsigned r  = (unsigned)((rec >> 34) & 0x1FFull);
        e = (unsigned)(rec >> 43);

        const uint4 ua = *(const uint4*)(A + (size_t)h * EMB + k * 8);
        const uint32x4 ub = __builtin_nontemporal_load(
            (const uint32x4*)(B + (size_t)tt * EMB + k * 8));
        const uint4 ur = *(const uint4*)(Rbf + (size_t)r * EMB + k * 8);

        s  = fmaxf(bf2f_lo(ua.x) + bf2f_lo(ur.x) + bf2f_lo(ub[0]), 0.0f) * w0.x;
        s += fmaxf(bf2f_hi(ua.x) + bf2f_hi(ur.x) + bf2f_hi(ub[0]), 0.0f) * w0.y;
        s += fmaxf(bf2f_lo(ua.y) + bf2f_lo(ur.y) + bf2f_lo(ub[1]), 0.0f) * w0.z;
        s += fmaxf(bf2f_hi(ua.y) + bf2f_hi(ur.y) + bf2f_hi(ub[1]), 0.0f) * w0.w;
        s += fmaxf(bf2f_lo(ua.z) + bf2f_lo(ur.z) + bf2f_lo(ub[2]), 0.0f) * w1.x;
        s += fmaxf(bf2f_hi(ua.z) + bf2f_hi(ur.z) + bf2f_hi(ub[2]), 0.0f) * w1.y;
        s += fmaxf(bf2f_lo(ua.w) + bf2f_lo(ur.w) + bf2f_lo(ub[3]), 0.0f) * w1.z;
        s += fmaxf(bf2f_hi(ua.w) + bf2f_hi(ur.w) + bf2f_hi(ub[3]), 0.0f) * w1.w;
    }
    s += __shfl_xor(s, 1, 64);
    s += __shfl_xor(s, 2, 64);
    s += __shfl_xor(s, 4, 64);
    s += __shfl_xor(s, 8, 64);
    if (k == 0 && valid) out[e] = s + b2[0];
}

// K4 legacy (fallback when workspace can't hold perm): unbucketed gathers.
__global__ __launch_bounds__(256) void edge_pred(
    const int* __restrict__ h_id, const int* __restrict__ r_id,
    const int* __restrict__ t_id,
    const u16* __restrict__ A, const u16* __restrict__ B,
    const u16* __restrict__ Rbf,
    const float* __restrict__ W2, const float* __restrict__ b2,
    float* __restrict__ out, int E)
{
    const int t    = threadIdx.x;
    const int lane = t & 63;
    const int g    = lane >> 4;
    const int k    = lane & 15;
    const int wv   = t >> 6;
    const int e    = blockIdx.x * 16 + wv * 4 + g;

    const float4 w0 = *(const float4*)(W2 + k * 8);
    const float4 w1 = *(const float4*)(W2 + k * 8 + 4);

    float s = 0.0f;
    if (e < E) {
        const int h = h_id[e], r = r_id[e], tt = t_id[e];
        const uint4 ua = *(const uint4*)(A + (size_t)h * EMB + k * 8);
        const uint4 ub = *(const uint4*)(B + (size_t)tt * EMB + k * 8);
        const uint4 ur = *(const uint4*)(Rbf + (size_t)r * EMB + k * 8);

        s  = fmaxf(bf2f_lo(ua.x) + bf2f_lo(ur.x) + bf2f_lo(ub.x), 0.0f) * w0.x;
        s += fmaxf(bf2f_hi(ua.x) + bf2f_hi(ur.x) + bf2f_hi(ub.x), 0.0f) * w0.y;
        s += fmaxf(bf2f_lo(ua.y) + bf2f_lo(ur.y) + bf2f_lo(ub.y), 0.0f) * w0.z;
        s += fmaxf(bf2f_hi(ua.y) + bf2f_hi(ur.y) + bf2f_hi(ub.y), 0.0f) * w0.w;
        s += fmaxf(bf2f_lo(ua.z) + bf2f_lo(ur.z) + bf2f_lo(ub.z), 0.0f) * w1.x;
        s += fmaxf(bf2f_hi(ua.z) + bf2f_hi(ur.z) + bf2f_hi(ub.z), 0.0f) * w1.y;
        s += fmaxf(bf2f_lo(ua.w) + bf2f_lo(ur.w) + bf2f_lo(ub.w), 0.0f) * w1.z;
        s += fmaxf(bf2f_hi(ua.w) + bf2f_hi(ur.w) + bf2f_hi(ub.w), 0.0f) * w1.w;
    }
    s += __shfl_xor(s, 1, 64);
    s += __shfl_xor(s, 2, 64);
    s += __shfl_xor(s, 4, 64);
    s += __shfl_xor(s, 8, 64);
    if (k == 0 && e < E) out[e] = s + b2[0];
}

// ---------------------------------------------------------------------------

extern "C" void kernel_launch(void* const* d_in, const int* in_sizes, int n_in,
                              void* d_out, int out_size, void* d_ws, size_t ws_size,
                              hipStream_t stream)
{
    const int*   h_id  = (const int*)d_in[0];
    const int*   r_id  = (const int*)d_in[1];
    const int*   t_id  = (const int*)d_in[2];
    const float* q_emb = (const float*)d_in[3];
    const float* ent   = (const float*)d_in[4];
    const float* rel   = (const float*)d_in[6];
    const float* topic = (const float*)d_in[7];
    const float* nte   = (const float*)d_in[8];
    const float* W1    = (const float*)d_in[9];
    const float* b1    = (const float*)d_in[10];
    const float* W2    = (const float*)d_in[11];
    const float* b2    = (const float*)d_in[12];

    const int E    = in_sizes[0];
    const int NT   = in_sizes[4] / EMB;  // 80000 text entities
    const int N    = in_sizes[7] / 2;    // 100000 total nodes
    const int NREL = in_sizes[6] / EMB;  // 500 relations

    // workspace layout:
    // [acc 4N u64][meta 32 u32][qWb][Rbf][WBF][Aw][Bw][perm E u64 (optional)]
    u64* acc1_t = (u64*)d_ws;                    // N
    u64* acc1_h = acc1_t + N;                    // N
    u64* acc2_t = acc1_h + N;                    // N
    u64* acc2_h = acc2_t + N;                    // N
    unsigned* bcnt = (unsigned*)(acc2_h + N);    // 8
    unsigned* bcur = bcnt + 8;                   // 8
    unsigned* boff = bcnt + 16;                  // 8 (+8 pad)
    float* qWb  = (float*)(bcnt + 32);           // 128
    u16* Rbf    = (u16*)(qWb + EMB);             // NREL*128 bf16
    u16* WBF    = Rbf + (size_t)NREL * EMB;      // KP*256 bf16
    u16* Aw     = WBF + (size_t)KP * 256;        // N*128 bf16
    u16* Bw     = Aw + (size_t)N * EMB;          // N*128 bf16
    u64* perm   = (u64*)(Bw + (size_t)N * EMB);  // E u64

    size_t need_bkt = (size_t)((char*)(perm + E) - (char*)d_ws);
    const bool bkt = (ws_size >= need_bkt) && (N <= 131072) &&
                     (NREL <= 512) && (E < (1 << 21));

    const int ns = (E + 255) / 256;      // scatter / perm blocks
    const int nn = (N + 31) / 32;        // node blocks
    const int nmax = (ns > nn) ? ns : nn;
    const int bsz = (N + 7) / 8;         // nodes per bucket

    hipMemsetAsync(d_ws, 0, sizeof(u64) * (size_t)(4 * N) + 128, stream);

    if (bkt) {
        k_bin<<<ns, 256, 0, stream>>>(h_id, bcnt, E, bsz);
        k_off<<<1, 64, 0, stream>>>(bcnt, boff, bcur);
    }

    k1_scatter1_prep<<<ns + KP + 1 + NREL + (bkt ? ns : 0), 256, 0, stream>>>(
        h_id, r_id, t_id, topic, acc1_t, acc1_h,
        W1, q_emb, rel, b1, WBF, qWb, Rbf, perm, bcur, E, ns, NREL, bsz);

    k2_scatter2_node<<<2 * nmax, 256, 0, stream>>>(
        h_id, t_id, acc1_t, acc1_h, acc2_t, acc2_h,
        ent, nte, topic, WBF, qWb, Aw, Bw, E, ns, NT, N, nn);

    k3_fixup<<<(N + 31) / 32, 256, 0, stream>>>(
        acc1_t, acc1_h, acc2_t, acc2_h, W1, Aw, Bw, N);

    if (bkt) {
        // per-bucket capacity 1.5x the uniform expectation (uniform-random h
        // makes overflow probability ~0; early-exit blocks are ~free)
        const int capb = (int)(((long long)E * 3 / 2) / (8 * 16)) + 2;
        edge_pred_bkt<<<8 * capb, 256, 0, stream>>>(
            perm, boff, bcnt, Aw, Bw, Rbf, W2, b2, (float*)d_out);
    } else {
        edge_pred<<<(E + 15) / 16, 256, 0, stream>>>(
            h_id, r_id, t_id, Aw, Bw, Rbf, W2, b2, (float*)d_out, E);
    }
}

// Round 4
// 256.274 us; speedup vs baseline: 1.6217x; 1.6217x over previous
//
#include <hip/hip_runtime.h>

#define EMB 128
#define W1LD 532   // PRED_IN
#define KP 160     // padded K for MFMA (138 -> 160)
#define ST 264     // LDS row stride (u16) in node path
#define BSH 9      // bucket shift: 512 nodes per bucket
#define BNODES 512
#define EPB 8192   // edges per sort block (1024 thr x 8 chunks)

typedef unsigned long long u64;
typedef unsigned int u32;
typedef unsigned short u16;
typedef __attribute__((ext_vector_type(8))) short short8;
typedef __attribute__((ext_vector_type(4))) float f32x4;

__device__ __forceinline__ u16 f2bf(float x) {
    unsigned u = __float_as_uint(x);
    unsigned r = (u + 0x7fffu + ((u >> 16) & 1u)) >> 16;
    return (u16)r;
}
__device__ __forceinline__ float bf2f_lo(unsigned u) { return __uint_as_float(u << 16); }
__device__ __forceinline__ float bf2f_hi(unsigned u) { return __uint_as_float(u & 0xffff0000u); }

// ---------------------------------------------------------------------------
// khist: per-sort-block bucket histograms, both directions.
// hist layout: [row][sb], row = dir*NBKT + bkt  (row-major, NSB stride)
// ---------------------------------------------------------------------------
__global__ __launch_bounds__(1024) void khist(
    const int* __restrict__ h_id, const int* __restrict__ t_id,
    u32* __restrict__ hist, int E, int NBKT, int NSB)
{
    __shared__ u32 lh[512];
    const int t = threadIdx.x, sb = blockIdx.x;
    const int rows = 2 * NBKT;
    if (t < rows) lh[t] = 0;
    __syncthreads();
    const int base = sb * EPB;
#pragma unroll
    for (int c = 0; c < EPB / 1024; c++) {
        int e = base + c * 1024 + t;
        if (e < E) {
            atomicAdd(&lh[t_id[e] >> BSH], 1u);
            atomicAdd(&lh[NBKT + (h_id[e] >> BSH)], 1u);
        }
    }
    __syncthreads();
    if (t < rows) hist[t * NSB + sb] = lh[t];
}

// ---------------------------------------------------------------------------
// kscanA: per-row exclusive scan over sort-blocks (in place) + row totals.
// Requires NSB <= 256. Grid = 2*NBKT rows.
// ---------------------------------------------------------------------------
__global__ __launch_bounds__(256) void kscanA(
    u32* __restrict__ hist, u32* __restrict__ tot, int NSB)
{
    __shared__ u32 s[256];
    const int t = threadIdx.x, row = blockIdx.x;
    u32 v = (t < NSB) ? hist[row * NSB + t] : 0;
    s[t] = v;
    __syncthreads();
    for (int o = 1; o < 256; o <<= 1) {
        u32 x = (t >= o) ? s[t - o] : 0;
        __syncthreads();
        s[t] += x;
        __syncthreads();
    }
    if (t < NSB) hist[row * NSB + t] = s[t] - v;   // exclusive prefix
    if (t == 255) tot[row] = s[255];
}

// ---------------------------------------------------------------------------
// kplace: write bucket-major permutations for both directions.
// Each (sort-block, bucket) owns the disjoint range base[bkt]+prefix[bkt][sb].
// Placement cursors live in LDS -> zero global atomics.
// rec = src(17b) | dstLow(9b)<<17   (src < 2^17, BNODES=512)
// Block 0 also writes bstart[dir][bkt] (bucket bases) for the scatter passes.
// ---------------------------------------------------------------------------
__global__ __launch_bounds__(1024) void kplace(
    const int* __restrict__ h_id, const int* __restrict__ t_id,
    const u32* __restrict__ hist, const u32* __restrict__ tot,
    u32* __restrict__ bstart,
    u32* __restrict__ perm_t, u32* __restrict__ perm_h,
    int E, int NBKT, int NSB)
{
    __shared__ u32 cur[512];
    const int t = threadIdx.x, sb = blockIdx.x;
    const int rows = 2 * NBKT;
    if (t < rows) {
        const int d  = (t < NBKT) ? 1 : 0;   // 1 => t-dir rows [0,NBKT)
        const int b0 = (t < NBKT) ? 0 : NBKT;
        u32 base = 0;
        for (int b = b0; b < t; b++) base += tot[b];
        cur[t] = base + hist[t * NSB + sb];
        if (sb == 0) {
            const int seg = (t < NBKT) ? 0 : (NBKT + 1);
            bstart[seg + (t - b0)] = base;
            if (t == b0) bstart[seg + NBKT] = (u32)E;
        }
        (void)d;
    }
    __syncthreads();
    const int ebase = sb * EPB;
#pragma unroll
    for (int c = 0; c < EPB / 1024; c++) {
        int e = ebase + c * 1024 + t;
        if (e < E) {
            int tt = t_id[e], h = h_id[e];
            u32 pt = atomicAdd(&cur[tt >> BSH], 1u);
            perm_t[pt] = (u32)h | ((u32)(tt & (BNODES - 1)) << 17);
            u32 ph = atomicAdd(&cur[NBKT + (h >> BSH)], 1u);
            perm_h[ph] = (u32)tt | ((u32)(h & (BNODES - 1)) << 17);
        }
    }
}

// ---------------------------------------------------------------------------
// kscat<ROUND>: LDS-accumulated scatter-mean, one block per (dir,bucket).
// pack: [x*2^20 : 26b][y*2^20 : 26b][cnt : 12b] -- integer adds, order-free.
// ROUND=1 src = topic; ROUND=2 src = dde1f (t-dir) / dde3f (h-dir).
// ROUND=1 grid also carries the prep blocks (WBF / qWb / Rbf).
// ---------------------------------------------------------------------------
template<int ROUND>
__global__ __launch_bounds__(256) void kscat(
    const u32* __restrict__ perm_t, const u32* __restrict__ perm_h,
    const u32* __restrict__ bstart,
    const float* __restrict__ topic,
    const float* __restrict__ src_t, const float* __restrict__ src_h,
    float* __restrict__ out_t, float* __restrict__ out_h,
    const float* __restrict__ W1, const float* __restrict__ q,
    const float* __restrict__ rel, const float* __restrict__ b1,
    u16* __restrict__ WBF, float* __restrict__ qWb, u16* __restrict__ Rbf,
    int N, int NBKT, int NREL)
{
    const int bid = blockIdx.x, t = threadIdx.x;
    if (bid < 2 * NBKT) {
        __shared__ u64 acc[BNODES];
        const int d = (bid < NBKT) ? 0 : 1;          // 0: t-dir, 1: h-dir
        const int b = bid - d * NBKT;
        const u32* perm = d ? perm_h : perm_t;
        const float* srcv = (ROUND == 1) ? topic : (d ? src_h : src_t);
        float* out = d ? out_h : out_t;

        for (int i = t; i < BNODES; i += 256) acc[i] = 0;
        __syncthreads();
        const u32 s0 = bstart[d * (NBKT + 1) + b];
        const u32 s1 = bstart[d * (NBKT + 1) + b + 1];
        for (u32 i = s0 + t; i < s1; i += 256) {
            u32 rec  = perm[i];
            u32 src  = rec & 0x1FFFFu;
            u32 slot = rec >> 17;
            float2 v = *(const float2*)(srcv + 2 * src);
            u64 p = (u64)__float2uint_rn(v.x * 1048576.0f)
                  | ((u64)__float2uint_rn(v.y * 1048576.0f) << 26)
                  | (1ull << 52);
            atomicAdd(&acc[slot], p);
        }
        __syncthreads();
        for (int i = t; i < BNODES; i += 256) {
            int node = b * BNODES + i;
            if (node < N) {
                u64 a = acc[i];
                float cnt = (float)(u32)(a >> 52);
                float inv = (1.0f / 1048576.0f) / fmaxf(cnt, 1.0f);
                float2 m;
                m.x = (float)(u32)(a & 0x3FFFFFFu) * inv;
                m.y = (float)(u32)((a >> 26) & 0x3FFFFFFu) * inv;
                *(float2*)(out + 2 * node) = m;
            }
        }
        return;
    }
    if (ROUND != 1) return;
    // ---------------- prep blocks (round 1 only) ----------------
    const int pb = bid - 2 * NBKT;
    if (pb < KP) {
        int k = pb, n = t;
        float v = 0.0f;
        if (k < 138) {
            v = (n < 128) ? W1[(size_t)n * W1LD + 128 + k]
                          : W1[(size_t)(n - 128) * W1LD + 394 + k];
        }
        int kstep = k >> 5, quad = (k >> 3) & 3, j = k & 7;
        WBF[(((size_t)(kstep * 4 + quad) * 256 + n) << 3) + j] = f2bf(v);
        return;
    }
    int b = pb - KP;   // 0 -> qWb ; 1..NREL -> relation b-1
    __shared__ float v[EMB];
    if (t < EMB) v[t] = (b == 0) ? q[t] : rel[(size_t)(b - 1) * EMB + t];
    __syncthreads();
    if (t < EMB) {
        const float* w = W1 + (size_t)t * W1LD + (b == 0 ? 0 : 266);
        float s = 0.0f;
#pragma unroll
        for (int k = 0; k < EMB; k += 4) {
            float4 wv = *(const float4*)(w + k);
            s += wv.x * v[k] + wv.y * v[k + 1] + wv.z * v[k + 2] + wv.w * v[k + 3];
        }
        if (b == 0) qWb[t] = s + b1[t];
        else        Rbf[(size_t)(b - 1) * EMB + t] = f2bf(s);
    }
}

// ---------------------------------------------------------------------------
// k2b_node: node MFMA GEMM with FULL tails (topic + all 8 dde dims staged);
// scatter is complete before this launches, so no fixup pass is needed.
// ---------------------------------------------------------------------------
__global__ __launch_bounds__(256) void k2b_node(
    const float* __restrict__ ent, const float* __restrict__ nte,
    const float* __restrict__ topic,
    const float* __restrict__ dde1f, const float* __restrict__ dde2f,
    const float* __restrict__ dde3f, const float* __restrict__ dde4f,
    const u16* __restrict__ WBF, const float* __restrict__ qWb,
    u16* __restrict__ A, u16* __restrict__ B,
    int NT, int N)
{
    __shared__ __align__(16) u16 lds[32 * ST];
    const int t = threadIdx.x;
    const int lane = t & 63;
    const int w    = t >> 6;
    const int ln15 = lane & 15;
    const int quad = lane >> 4;
    const int m0   = (w & 1) * 16;
    const int n0   = (w >> 1) * 128;
    const int nblk = blockIdx.x * 32;

    {   // stage dense features as bf16: thread -> node m=t>>3, 16 k-elems
        int m  = t >> 3;
        int kq = (t & 7) << 4;
        int gn = nblk + m;
        const float* src = (gn < N) ? ((gn < NT) ? ent + (size_t)gn * EMB + kq
                                                 : nte + kq)
                                    : nte;
        u16 pk[16];
#pragma unroll
        for (int p = 0; p < 4; p++) {
            float4 v = (gn < N) ? *(const float4*)(src + 4 * p)
                                : make_float4(0.f, 0.f, 0.f, 0.f);
            pk[4 * p + 0] = f2bf(v.x); pk[4 * p + 1] = f2bf(v.y);
            pk[4 * p + 2] = f2bf(v.z); pk[4 * p + 3] = f2bf(v.w);
        }
        *(uint4*)&lds[m * ST + kq]     = *(uint4*)&pk[0];
        *(uint4*)&lds[m * ST + kq + 8] = *(uint4*)&pk[8];
    }
    // tail: topic(2) + dde1..4 (8) at k=128..137; 138..159 zero
    if (t < 32) {
        int gn = nblk + t;
        if (gn < N) {
            float2 tp = *(const float2*)(topic + 2 * gn);
            float2 d1 = *(const float2*)(dde1f + 2 * gn);
            float2 d2 = *(const float2*)(dde2f + 2 * gn);
            float2 d3 = *(const float2*)(dde3f + 2 * gn);
            float2 d4 = *(const float2*)(dde4f + 2 * gn);
            lds[t * ST + 128] = f2bf(tp.x); lds[t * ST + 129] = f2bf(tp.y);
            lds[t * ST + 130] = f2bf(d1.x); lds[t * ST + 131] = f2bf(d1.y);
            lds[t * ST + 132] = f2bf(d2.x); lds[t * ST + 133] = f2bf(d2.y);
            lds[t * ST + 134] = f2bf(d3.x); lds[t * ST + 135] = f2bf(d3.y);
            lds[t * ST + 136] = f2bf(d4.x); lds[t * ST + 137] = f2bf(d4.y);
        } else {
#pragma unroll
            for (int z = 128; z < 138; z++) lds[t * ST + z] = 0;
        }
#pragma unroll
        for (int z = 138; z < KP; z++) lds[t * ST + z] = 0;
    }
    __syncthreads();

    f32x4 acc[8];
#pragma unroll
    for (int i = 0; i < 8; i++) acc[i] = (f32x4){0.f, 0.f, 0.f, 0.f};

    const u16* wbbase = WBF + (((size_t)quad * 256 + n0 + ln15) << 3);
#pragma unroll
    for (int ks = 0; ks < 5; ks++) {
        short8 a = *(const short8*)&lds[(m0 + ln15) * ST + ks * 32 + quad * 8];
        const u16* wb = wbbase + ((size_t)ks * 4 * 256 * 8);
#pragma unroll
        for (int nt = 0; nt < 8; nt++) {
            short8 b = *(const short8*)(wb + (nt << 7));
            acc[nt] = __builtin_amdgcn_mfma_f32_16x16x32_bf16(a, b, acc[nt], 0, 0, 0);
        }
    }

    __syncthreads();   // all a-frag reads done before overwrite
#pragma unroll
    for (int nt = 0; nt < 8; nt++) {
        int c = n0 + nt * 16 + ln15;
        float qv = (n0 == 0) ? qWb[c] : 0.0f;
#pragma unroll
        for (int r = 0; r < 4; r++) {
            int row = m0 + quad * 4 + r;
            lds[row * ST + c] = f2bf(acc[nt][r] + qv);
        }
    }
    __syncthreads();
    {
        int m  = t >> 3;
        int c0 = (t & 7) * 32;
        int gn = nblk + m;
        if (gn < N) {
            uint4 v0 = *(uint4*)&lds[m * ST + c0];
            uint4 v1 = *(uint4*)&lds[m * ST + c0 + 8];
            uint4 v2 = *(uint4*)&lds[m * ST + c0 + 16];
            uint4 v3 = *(uint4*)&lds[m * ST + c0 + 24];
            u16* dst = (c0 < 128) ? (A + (size_t)gn * EMB + c0)
                                  : (B + (size_t)gn * EMB + (c0 - 128));
            ((uint4*)dst)[0] = v0;
            ((uint4*)dst)[1] = v1;
            ((uint4*)dst)[2] = v2;
            ((uint4*)dst)[3] = v3;
        }
    }
}

// ---------------------------------------------------------------------------
// K4 edge kernel: 16 lanes/edge, 8 elems/lane, 4 edges/wave; uint4 gathers.
// ---------------------------------------------------------------------------
__global__ __launch_bounds__(256) void edge_pred(
    const int* __restrict__ h_id, const int* __restrict__ r_id,
    const int* __restrict__ t_id,
    const u16* __restrict__ A, const u16* __restrict__ B,
    const u16* __restrict__ Rbf,
    const float* __restrict__ W2, const float* __restrict__ b2,
    float* __restrict__ out, int E)
{
    const int t    = threadIdx.x;
    const int lane = t & 63;
    const int g    = lane >> 4;
    const int k    = lane & 15;
    const int wv   = t >> 6;
    const int e    = blockIdx.x * 16 + wv * 4 + g;

    const float4 w0 = *(const float4*)(W2 + k * 8);
    const float4 w1 = *(const float4*)(W2 + k * 8 + 4);

    float s = 0.0f;
    if (e < E) {
        const int h = h_id[e], r = r_id[e], tt = t_id[e];
        const uint4 ua = *(const uint4*)(A + (size_t)h * EMB + k * 8);
        const uint4 ub = *(const uint4*)(B + (size_t)tt * EMB + k * 8);
        const uint4 ur = *(const uint4*)(Rbf + (size_t)r * EMB + k * 8);

        s  = fmaxf(bf2f_lo(ua.x) + bf2f_lo(ur.x) + bf2f_lo(ub.x), 0.0f) * w0.x;
        s += fmaxf(bf2f_hi(ua.x) + bf2f_hi(ur.x) + bf2f_hi(ub.x), 0.0f) * w0.y;
        s += fmaxf(bf2f_lo(ua.y) + bf2f_lo(ur.y) + bf2f_lo(ub.y), 0.0f) * w0.z;
        s += fmaxf(bf2f_hi(ua.y) + bf2f_hi(ur.y) + bf2f_hi(ub.y), 0.0f) * w0.w;
        s += fmaxf(bf2f_lo(ua.z) + bf2f_lo(ur.z) + bf2f_lo(ub.z), 0.0f) * w1.x;
        s += fmaxf(bf2f_hi(ua.z) + bf2f_hi(ur.z) + bf2f_hi(ub.z), 0.0f) * w1.y;
        s += fmaxf(bf2f_lo(ua.w) + bf2f_lo(ur.w) + bf2f_lo(ub.w), 0.0f) * w1.z;
        s += fmaxf(bf2f_hi(ua.w) + bf2f_hi(ur.w) + bf2f_hi(ub.w), 0.0f) * w1.w;
    }
    s += __shfl_xor(s, 1, 64);
    s += __shfl_xor(s, 2, 64);
    s += __shfl_xor(s, 4, 64);
    s += __shfl_xor(s, 8, 64);
    if (k == 0 && e < E) out[e] = s + b2[0];
}

// ---------------------------------------------------------------------------

extern "C" void kernel_launch(void* const* d_in, const int* in_sizes, int n_in,
                              void* d_out, int out_size, void* d_ws, size_t ws_size,
                              hipStream_t stream)
{
    const int*   h_id  = (const int*)d_in[0];
    const int*   r_id  = (const int*)d_in[1];
    const int*   t_id  = (const int*)d_in[2];
    const float* q_emb = (const float*)d_in[3];
    const float* ent   = (const float*)d_in[4];
    const float* rel   = (const float*)d_in[6];
    const float* topic = (const float*)d_in[7];
    const float* nte   = (const float*)d_in[8];
    const float* W1    = (const float*)d_in[9];
    const float* b1    = (const float*)d_in[10];
    const float* W2    = (const float*)d_in[11];
    const float* b2    = (const float*)d_in[12];

    const int E    = in_sizes[0];
    const int NT   = in_sizes[4] / EMB;  // 80000 text entities
    const int N    = in_sizes[7] / 2;    // 100000 total nodes
    const int NREL = in_sizes[6] / EMB;  // 500 relations

    const int NBKT = (N + BNODES - 1) >> BSH;      // 196
    const int NSB  = (E + EPB - 1) / EPB;          // 98  (must be <= 256)

    // workspace: [qWb][Rbf][WBF][dde1..4 f32x2][Aw][Bw]
    // sort scratch (hist/tot/bstart/perm_t/perm_h) aliases into Aw/Bw:
    // its lifetime ends at kscat2, before the GEMM writes A/B.
    float* qWb  = (float*)d_ws;                      // 128
    u16* Rbf    = (u16*)(qWb + EMB);                 // NREL*128 bf16
    u16* WBF    = Rbf + (size_t)NREL * EMB;          // KP*256 bf16
    float* dde1f = (float*)(WBF + (size_t)KP * 256); // N float2
    float* dde2f = dde1f + 2 * (size_t)N;
    float* dde3f = dde2f + 2 * (size_t)N;
    float* dde4f = dde3f + 2 * (size_t)N;
    u16* Aw = (u16*)(dde4f + 2 * (size_t)N);         // N*128 bf16
    u16* Bw = Aw + (size_t)N * EMB;                  // N*128 bf16

    u32* hist   = (u32*)Aw;                          // 2*NBKT*NSB
    u32* tot    = hist + (size_t)2 * NBKT * NSB;     // 2*NBKT
    u32* bstart = tot + 2 * NBKT;                    // 2*(NBKT+1)
    u32* perm_t = bstart + 2 * (NBKT + 1);           // E
    u32* perm_h = perm_t + E;                        // E

    const int nn = (N + 31) / 32;                    // node GEMM blocks

    // ---- counting sort (both directions), zero global atomics ----
    khist<<<NSB, 1024, 0, stream>>>(h_id, t_id, hist, E, NBKT, NSB);
    kscanA<<<2 * NBKT, 256, 0, stream>>>(hist, tot, NSB);
    kplace<<<NSB, 1024, 0, stream>>>(h_id, t_id, hist, tot, bstart,
                                     perm_t, perm_h, E, NBKT, NSB);

    // ---- scatter round 1 (+ weight/relation prep in extra blocks) ----
    kscat<1><<<2 * NBKT + KP + 1 + NREL, 256, 0, stream>>>(
        perm_t, perm_h, bstart, topic, nullptr, nullptr, dde1f, dde3f,
        W1, q_emb, rel, b1, WBF, qWb, Rbf, N, NBKT, NREL);

    // ---- scatter round 2 ----
    kscat<2><<<2 * NBKT, 256, 0, stream>>>(
        perm_t, perm_h, bstart, topic, dde1f, dde3f, dde2f, dde4f,
        W1, q_emb, rel, b1, WBF, qWb, Rbf, N, NBKT, NREL);

    // ---- node GEMM with full tails (overwrites sort scratch) ----
    k2b_node<<<nn, 256, 0, stream>>>(
        ent, nte, topic, dde1f, dde2f, dde3f, dde4f,
        WBF, qWb, Aw, Bw, NT, N);

    // ---- edge prediction ----
    edge_pred<<<(E + 15) / 16, 256, 0, stream>>>(
        h_id, r_id, t_id, Aw, Bw, Rbf, W2, b2, (float*)d_out, E);
}

// Round 5
// 248.981 us; speedup vs baseline: 1.6692x; 1.0293x over previous
//
#include <hip/hip_runtime.h>

#define EMB 128
#define W1LD 532   // PRED_IN
#define KP 160     // padded K for MFMA (138 -> 160)
#define ST 264     // LDS row stride (u16) in node path
#define BSH 9      // bucket shift: 512 nodes per bucket
#define BNODES 512
#define EPB 4096   // edges per sort block (1024 thr x 4 chunks)

typedef unsigned long long u64;
typedef unsigned int u32;
typedef unsigned short u16;
typedef __attribute__((ext_vector_type(8))) short short8;
typedef __attribute__((ext_vector_type(4))) float f32x4;
typedef _Float16 h2 __attribute__((ext_vector_type(2)));

__device__ __forceinline__ u16 f2bf(float x) {
    unsigned u = __float_as_uint(x);
    unsigned r = (u + 0x7fffu + ((u >> 16) & 1u)) >> 16;
    return (u16)r;
}
__device__ __forceinline__ u16 f2h(float x) {
    union { _Float16 h; u16 u; } c; c.h = (_Float16)x; return c.u;
}
__device__ __forceinline__ h2 u2h(unsigned u) {
    union { unsigned u; h2 h; } c; c.u = u; return c.h;
}

// packed f16 triple-add + relu + dot2 accumulate (8 elems = 4 u32 lanes)
__device__ __forceinline__ float ep8(const uint4& ua, const uint4& ub,
                                     const uint4& ur, const uint4& uw, float s) {
    const h2 z = {(_Float16)0.0f, (_Float16)0.0f};
#define EP1(c)                                                         \
    {                                                                  \
        h2 x = u2h(ua.c) + u2h(ur.c) + u2h(ub.c);                      \
        x = __builtin_elementwise_max(x, z);                           \
        h2 w = u2h(uw.c);                                              \
        _Pragma("clang diagnostic push")                               \
        s = FDOT2(x, w, s);                                            \
        _Pragma("clang diagnostic pop")                                \
    }
#if __has_builtin(__builtin_amdgcn_fdot2)
#define FDOT2(x, w, s) __builtin_amdgcn_fdot2(x, w, s, false)
#else
#define FDOT2(x, w, s) (s + (float)x[0] * (float)w[0] + (float)x[1] * (float)w[1])
#endif
    EP1(x) EP1(y) EP1(z) EP1(w)
#undef EP1
#undef FDOT2
    return s;
}

// ---------------------------------------------------------------------------
// khist: per-sort-block bucket histograms, both directions.
// ---------------------------------------------------------------------------
__global__ __launch_bounds__(1024) void khist(
    const int* __restrict__ h_id, const int* __restrict__ t_id,
    u32* __restrict__ hist, int E, int NBKT, int NSB)
{
    __shared__ u32 lh[512];
    const int t = threadIdx.x, sb = blockIdx.x;
    const int rows = 2 * NBKT;
    if (t < rows) lh[t] = 0;
    __syncthreads();
    const int base = sb * EPB;
#pragma unroll
    for (int c = 0; c < EPB / 1024; c++) {
        int e = base + c * 1024 + t;
        if (e < E) {
            atomicAdd(&lh[t_id[e] >> BSH], 1u);
            atomicAdd(&lh[NBKT + (h_id[e] >> BSH)], 1u);
        }
    }
    __syncthreads();
    if (t < rows) hist[t * NSB + sb] = lh[t];
}

// ---------------------------------------------------------------------------
// kscanA: per-row exclusive scan over sort-blocks + row totals (NSB <= 256).
// ---------------------------------------------------------------------------
__global__ __launch_bounds__(256) void kscanA(
    u32* __restrict__ hist, u32* __restrict__ tot, int NSB)
{
    __shared__ u32 s[256];
    const int t = threadIdx.x, row = blockIdx.x;
    u32 v = (t < NSB) ? hist[row * NSB + t] : 0;
    s[t] = v;
    __syncthreads();
    for (int o = 1; o < 256; o <<= 1) {
        u32 x = (t >= o) ? s[t - o] : 0;
        __syncthreads();
        s[t] += x;
        __syncthreads();
    }
    if (t < NSB) hist[row * NSB + t] = s[t] - v;
    if (t == 255) tot[row] = s[255];
}

// ---------------------------------------------------------------------------
// kplace: bucket-major permutations. LDS placement cursors -> no global
// atomics. perm_t (u32): h | (t&511)<<17  (t-dir scatter).
// perm_e (u64): h | t<<17 | r<<34 | e<<43 (h-dir scatter AND sorted k4).
// ---------------------------------------------------------------------------
__global__ __launch_bounds__(1024) void kplace(
    const int* __restrict__ h_id, const int* __restrict__ r_id,
    const int* __restrict__ t_id,
    const u32* __restrict__ hist, const u32* __restrict__ tot,
    u32* __restrict__ bstart,
    u32* __restrict__ perm_t, u64* __restrict__ perm_e,
    int E, int NBKT, int NSB)
{
    __shared__ u32 cur[512];
    const int t = threadIdx.x, sb = blockIdx.x;
    const int rows = 2 * NBKT;
    if (t < rows) {
        const int b0 = (t < NBKT) ? 0 : NBKT;
        u32 base = 0;
        for (int b = b0; b < t; b++) base += tot[b];
        cur[t] = base + hist[t * NSB + sb];
        if (sb == 0) {
            const int seg = (t < NBKT) ? 0 : (NBKT + 1);
            bstart[seg + (t - b0)] = base;
            if (t == b0) bstart[seg + NBKT] = (u32)E;
        }
    }
    __syncthreads();
    const int ebase = sb * EPB;
#pragma unroll
    for (int c = 0; c < EPB / 1024; c++) {
        int e = ebase + c * 1024 + t;
        if (e < E) {
            int tt = t_id[e], h = h_id[e], r = r_id[e];
            u32 pt = atomicAdd(&cur[tt >> BSH], 1u);
            perm_t[pt] = (u32)h | ((u32)(tt & (BNODES - 1)) << 17);
            u32 ph = atomicAdd(&cur[NBKT + (h >> BSH)], 1u);
            perm_e[ph] = (u64)h | ((u64)tt << 17) | ((u64)r << 34)
                       | ((u64)e << 43);
        }
    }
}

// ---------------------------------------------------------------------------
// kscat<ROUND>: LDS-accumulated scatter-mean, one block per (dir,bucket).
// pack: [x*2^20:26][y*2^20:26][cnt:12]. ROUND=1 src=topic (+prep blocks);
// ROUND=2 src = dde1f (t-dir) / dde3f (h-dir).
// ---------------------------------------------------------------------------
template<int ROUND>
__global__ __launch_bounds__(256) void kscat(
    const u32* __restrict__ perm_t, const u64* __restrict__ perm_e,
    const u32* __restrict__ bstart,
    const float* __restrict__ topic,
    const float* __restrict__ src_t, const float* __restrict__ src_h,
    float* __restrict__ out_t, float* __restrict__ out_h,
    const float* __restrict__ W1, const float* __restrict__ q,
    const float* __restrict__ rel, const float* __restrict__ b1,
    const float* __restrict__ W2,
    u16* __restrict__ WBF, float* __restrict__ qWb,
    u16* __restrict__ W2h, u16* __restrict__ Rbf,
    int N, int NBKT, int NREL)
{
    const int bid = blockIdx.x, t = threadIdx.x;
    if (bid < 2 * NBKT) {
        __shared__ u64 acc[BNODES];
        const int d = (bid < NBKT) ? 0 : 1;          // 0: t-dir, 1: h-dir
        const int b = bid - d * NBKT;
        const float* srcv = (ROUND == 1) ? topic : (d ? src_h : src_t);
        float* out = d ? out_h : out_t;

        for (int i = t; i < BNODES; i += 256) acc[i] = 0;
        __syncthreads();
        const u32 s0 = bstart[d * (NBKT + 1) + b];
        const u32 s1 = bstart[d * (NBKT + 1) + b + 1];
        if (d == 0) {
            for (u32 i = s0 + t; i < s1; i += 256) {
                u32 rec  = perm_t[i];
                u32 src  = rec & 0x1FFFFu;
                u32 slot = rec >> 17;
                float2 v = *(const float2*)(srcv + 2 * src);
                u64 p = (u64)__float2uint_rn(v.x * 1048576.0f)
                      | ((u64)__float2uint_rn(v.y * 1048576.0f) << 26)
                      | (1ull << 52);
                atomicAdd(&acc[slot], p);
            }
        } else {
            for (u32 i = s0 + t; i < s1; i += 256) {
                u64 rec  = perm_e[i];
                u32 src  = (u32)(rec >> 17) & 0x1FFFFu;   // t
                u32 slot = (u32)rec & (BNODES - 1);        // h & 511
                float2 v = *(const float2*)(srcv + 2 * src);
                u64 p = (u64)__float2uint_rn(v.x * 1048576.0f)
                      | ((u64)__float2uint_rn(v.y * 1048576.0f) << 26)
                      | (1ull << 52);
                atomicAdd(&acc[slot], p);
            }
        }
        __syncthreads();
        for (int i = t; i < BNODES; i += 256) {
            int node = b * BNODES + i;
            if (node < N) {
                u64 a = acc[i];
                float cnt = (float)(u32)(a >> 52);
                float inv = (1.0f / 1048576.0f) / fmaxf(cnt, 1.0f);
                float2 m;
                m.x = (float)(u32)(a & 0x3FFFFFFu) * inv;
                m.y = (float)(u32)((a >> 26) & 0x3FFFFFFu) * inv;
                *(float2*)(out + 2 * node) = m;
            }
        }
        return;
    }
    if (ROUND != 1) return;
    // ---------------- prep blocks (round 1 only) ----------------
    const int pb = bid - 2 * NBKT;
    if (pb < KP) {
        int k = pb, n = t;
        float v = 0.0f;
        if (k < 138) {
            v = (n < 128) ? W1[(size_t)n * W1LD + 128 + k]
                          : W1[(size_t)(n - 128) * W1LD + 394 + k];
        }
        int kstep = k >> 5, quad = (k >> 3) & 3, j = k & 7;
        WBF[(((size_t)(kstep * 4 + quad) * 256 + n) << 3) + j] = f2bf(v);
        return;
    }
    int b = pb - KP;   // 0 -> qWb + W2h ; 1..NREL -> relation b-1
    __shared__ float v[EMB];
    if (t < EMB) v[t] = (b == 0) ? q[t] : rel[(size_t)(b - 1) * EMB + t];
    __syncthreads();
    if (t < EMB) {
        const float* w = W1 + (size_t)t * W1LD + (b == 0 ? 0 : 266);
        float s = 0.0f;
#pragma unroll
        for (int k = 0; k < EMB; k += 4) {
            float4 wv = *(const float4*)(w + k);
            s += wv.x * v[k] + wv.y * v[k + 1] + wv.z * v[k + 2] + wv.w * v[k + 3];
        }
        if (b == 0) { qWb[t] = s + b1[t]; W2h[t] = f2h(W2[t]); }
        else        Rbf[(size_t)(b - 1) * EMB + t] = f2h(s);
    }
}

// ---------------------------------------------------------------------------
// k2b_node: node MFMA GEMM with FULL tails; outputs A/B in **f16**.
// ---------------------------------------------------------------------------
__global__ __launch_bounds__(256) void k2b_node(
    const float* __restrict__ ent, const float* __restrict__ nte,
    const float* __restrict__ topic,
    const float* __restrict__ dde1f, const float* __restrict__ dde2f,
    const float* __restrict__ dde3f, const float* __restrict__ dde4f,
    const u16* __restrict__ WBF, const float* __restrict__ qWb,
    u16* __restrict__ A, u16* __restrict__ B,
    int NT, int N)
{
    __shared__ __align__(16) u16 lds[32 * ST];
    const int t = threadIdx.x;
    const int lane = t & 63;
    const int w    = t >> 6;
    const int ln15 = lane & 15;
    const int quad = lane >> 4;
    const int m0   = (w & 1) * 16;
    const int n0   = (w >> 1) * 128;
    const int nblk = blockIdx.x * 32;

    {   // stage dense features as bf16 (MFMA input)
        int m  = t >> 3;
        int kq = (t & 7) << 4;
        int gn = nblk + m;
        const float* src = (gn < N) ? ((gn < NT) ? ent + (size_t)gn * EMB + kq
                                                 : nte + kq)
                                    : nte;
        u16 pk[16];
#pragma unroll
        for (int p = 0; p < 4; p++) {
            float4 v = (gn < N) ? *(const float4*)(src + 4 * p)
                                : make_float4(0.f, 0.f, 0.f, 0.f);
            pk[4 * p + 0] = f2bf(v.x); pk[4 * p + 1] = f2bf(v.y);
            pk[4 * p + 2] = f2bf(v.z); pk[4 * p + 3] = f2bf(v.w);
        }
        *(uint4*)&lds[m * ST + kq]     = *(uint4*)&pk[0];
        *(uint4*)&lds[m * ST + kq + 8] = *(uint4*)&pk[8];
    }
    // tail: topic(2) + dde1..4 (8) at k=128..137; 138..159 zero
    if (t < 32) {
        int gn = nblk + t;
        if (gn < N) {
            float2 tp = *(const float2*)(topic + 2 * gn);
            float2 d1 = *(const float2*)(dde1f + 2 * gn);
            float2 d2 = *(const float2*)(dde2f + 2 * gn);
            float2 d3 = *(const float2*)(dde3f + 2 * gn);
            float2 d4 = *(const float2*)(dde4f + 2 * gn);
            lds[t * ST + 128] = f2bf(tp.x); lds[t * ST + 129] = f2bf(tp.y);
            lds[t * ST + 130] = f2bf(d1.x); lds[t * ST + 131] = f2bf(d1.y);
            lds[t * ST + 132] = f2bf(d2.x); lds[t * ST + 133] = f2bf(d2.y);
            lds[t * ST + 134] = f2bf(d3.x); lds[t * ST + 135] = f2bf(d3.y);
            lds[t * ST + 136] = f2bf(d4.x); lds[t * ST + 137] = f2bf(d4.y);
        } else {
#pragma unroll
            for (int z = 128; z < 138; z++) lds[t * ST + z] = 0;
        }
#pragma unroll
        for (int z = 138; z < KP; z++) lds[t * ST + z] = 0;
    }
    __syncthreads();

    f32x4 acc[8];
#pragma unroll
    for (int i = 0; i < 8; i++) acc[i] = (f32x4){0.f, 0.f, 0.f, 0.f};

    const u16* wbbase = WBF + (((size_t)quad * 256 + n0 + ln15) << 3);
#pragma unroll
    for (int ks = 0; ks < 5; ks++) {
        short8 a = *(const short8*)&lds[(m0 + ln15) * ST + ks * 32 + quad * 8];
        const u16* wb = wbbase + ((size_t)ks * 4 * 256 * 8);
#pragma unroll
        for (int nt = 0; nt < 8; nt++) {
            short8 b = *(const short8*)(wb + (nt << 7));
            acc[nt] = __builtin_amdgcn_mfma_f32_16x16x32_bf16(a, b, acc[nt], 0, 0, 0);
        }
    }

    __syncthreads();   // all a-frag reads done before overwrite
#pragma unroll
    for (int nt = 0; nt < 8; nt++) {
        int c = n0 + nt * 16 + ln15;
        float qv = (n0 == 0) ? qWb[c] : 0.0f;
#pragma unroll
        for (int r = 0; r < 4; r++) {
            int row = m0 + quad * 4 + r;
            lds[row * ST + c] = f2h(acc[nt][r] + qv);   // f16 output
        }
    }
    __syncthreads();
    {
        int m  = t >> 3;
        int c0 = (t & 7) * 32;
        int gn = nblk + m;
        if (gn < N) {
            uint4 v0 = *(uint4*)&lds[m * ST + c0];
            uint4 v1 = *(uint4*)&lds[m * ST + c0 + 8];
            uint4 v2 = *(uint4*)&lds[m * ST + c0 + 16];
            uint4 v3 = *(uint4*)&lds[m * ST + c0 + 24];
            u16* dst = (c0 < 128) ? (A + (size_t)gn * EMB + c0)
                                  : (B + (size_t)gn * EMB + (c0 - 128));
            ((uint4*)dst)[0] = v0;
            ((uint4*)dst)[1] = v1;
            ((uint4*)dst)[2] = v2;
            ((uint4*)dst)[3] = v3;
        }
    }
}

// ---------------------------------------------------------------------------
// K4 sorted: walk perm_e (h-bucket order) -> A gathers hit a 128KB L2-resident
// slice; out[e] scattered 4B (out is 3.2MB, L2-resident). f16 packed math.
// ---------------------------------------------------------------------------
__global__ __launch_bounds__(256) void edge_pred_srt(
    const u64* __restrict__ perm_e,
    const u16* __restrict__ A, const u16* __restrict__ B,
    const u16* __restrict__ Rbf, const u16* __restrict__ W2h,
    const float* __restrict__ b2, float* __restrict__ out, int E)
{
    const int t    = threadIdx.x;
    const int lane = t & 63;
    const int g    = lane >> 4;
    const int k    = lane & 15;
    const int wv   = t >> 6;
    const int i    = blockIdx.x * 16 + wv * 4 + g;
    const bool valid = i < E;

    const uint4 uw = *(const uint4*)(W2h + k * 8);
    float s = 0.0f;
    u32 e = 0;
    if (valid) {
        u64 rec = perm_e[i];
        u32 h  = (u32)rec & 0x1FFFFu;
        u32 tt = (u32)(rec >> 17) & 0x1FFFFu;
        u32 r  = (u32)(rec >> 34) & 0x1FFu;
        e = (u32)(rec >> 43);
        const uint4 ua = *(const uint4*)(A + (size_t)h * EMB + k * 8);
        const uint4 ub = *(const uint4*)(B + (size_t)tt * EMB + k * 8);
        const uint4 ur = *(const uint4*)(Rbf + (size_t)r * EMB + k * 8);
        s = ep8(ua, ub, ur, uw, 0.0f);
    }
    s += __shfl_xor(s, 1, 64);
    s += __shfl_xor(s, 2, 64);
    s += __shfl_xor(s, 4, 64);
    s += __shfl_xor(s, 8, 64);
    if (k == 0 && valid) out[e] = s + b2[0];
}

// K4 fallback (unsorted, f16 math) when workspace can't hold dedicated perm.
__global__ __launch_bounds__(256) void edge_pred_f16(
    const int* __restrict__ h_id, const int* __restrict__ r_id,
    const int* __restrict__ t_id,
    const u16* __restrict__ A, const u16* __restrict__ B,
    const u16* __restrict__ Rbf, const u16* __restrict__ W2h,
    const float* __restrict__ b2, float* __restrict__ out, int E)
{
    const int t    = threadIdx.x;
    const int lane = t & 63;
    const int g    = lane >> 4;
    const int k    = lane & 15;
    const int wv   = t >> 6;
    const int e    = blockIdx.x * 16 + wv * 4 + g;

    const uint4 uw = *(const uint4*)(W2h + k * 8);
    float s = 0.0f;
    if (e < E) {
        const int h = h_id[e], r = r_id[e], tt = t_id[e];
        const uint4 ua = *(const uint4*)(A + (size_t)h * EMB + k * 8);
        const uint4 ub = *(const uint4*)(B + (size_t)tt * EMB + k * 8);
        const uint4 ur = *(const uint4*)(Rbf + (size_t)r * EMB + k * 8);
        s = ep8(ua, ub, ur, uw, 0.0f);
    }
    s += __shfl_xor(s, 1, 64);
    s += __shfl_xor(s, 2, 64);
    s += __shfl_xor(s, 4, 64);
    s += __shfl_xor(s, 8, 64);
    if (k == 0 && e < E) out[e] = s + b2[0];
}

// ---------------------------------------------------------------------------

extern "C" void kernel_launch(void* const* d_in, const int* in_sizes, int n_in,
                              void* d_out, int out_size, void* d_ws, size_t ws_size,
                              hipStream_t stream)
{
    const int*   h_id  = (const int*)d_in[0];
    const int*   r_id  = (const int*)d_in[1];
    const int*   t_id  = (const int*)d_in[2];
    const float* q_emb = (const float*)d_in[3];
    const float* ent   = (const float*)d_in[4];
    const float* rel   = (const float*)d_in[6];
    const float* topic = (const float*)d_in[7];
    const float* nte   = (const float*)d_in[8];
    const float* W1    = (const float*)d_in[9];
    const float* b1    = (const float*)d_in[10];
    const float* W2    = (const float*)d_in[11];
    const float* b2    = (const float*)d_in[12];

    const int E    = in_sizes[0];
    const int NT   = in_sizes[4] / EMB;  // 80000 text entities
    const int N    = in_sizes[7] / 2;    // 100000 total nodes
    const int NREL = in_sizes[6] / EMB;  // 500 relations

    const int NBKT = (N + BNODES - 1) >> BSH;      // 196
    const int NSB  = (E + EPB - 1) / EPB;          // 196 (must be <= 256)

    // persistent layout: [qWb][W2h][Rbf][WBF][dde1..4][Aw][Bw][perm_e?]
    float* qWb  = (float*)d_ws;                      // 128 f32
    u16* W2h    = (u16*)(qWb + EMB);                 // 128 f16
    u16* Rbf    = W2h + EMB;                         // NREL*128 f16
    u16* WBF    = Rbf + (size_t)NREL * EMB;          // KP*256 bf16
    float* dde1f = (float*)(WBF + (size_t)KP * 256); // N float2
    float* dde2f = dde1f + 2 * (size_t)N;
    float* dde3f = dde2f + 2 * (size_t)N;
    float* dde4f = dde3f + 2 * (size_t)N;
    u16* Aw = (u16*)(dde4f + 2 * (size_t)N);         // N*128 f16
    u16* Bw = Aw + (size_t)N * EMB;                  // N*128 f16
    u64* perm_ded = (u64*)(Bw + (size_t)N * EMB);    // E u64 (sorted path)

    // sort scratch aliased into Aw/Bw (dead before k2b_node writes A/B)
    u32* hist   = (u32*)Aw;                          // 2*NBKT*NSB
    u32* tot    = hist + (size_t)2 * NBKT * NSB;     // 2*NBKT
    u32* bstart = tot + 2 * NBKT;                    // 2*(NBKT+1)
    u32* perm_t = bstart + 2 * (NBKT + 1);           // E
    u64* perm_alias = (u64*)(((size_t)(perm_t + E) + 7) & ~(size_t)7);

    size_t need_srt = (size_t)((char*)(perm_ded + E) - (char*)d_ws);
    const bool srt = (ws_size >= need_srt) && (E < (1 << 20)) &&
                     (N <= (1 << 17)) && (NREL <= (1 << 9)) && (NSB <= 256);
    u64* perm_e = srt ? perm_ded : perm_alias;

    const int nn = (N + 31) / 32;

    // ---- counting sort (both directions), zero global atomics ----
    khist<<<NSB, 1024, 0, stream>>>(h_id, t_id, hist, E, NBKT, NSB);
    kscanA<<<2 * NBKT, 256, 0, stream>>>(hist, tot, NSB);
    kplace<<<NSB, 1024, 0, stream>>>(h_id, r_id, t_id, hist, tot, bstart,
                                     perm_t, perm_e, E, NBKT, NSB);

    // ---- scatter round 1 (+ prep) ----
    kscat<1><<<2 * NBKT + KP + 1 + NREL, 256, 0, stream>>>(
        perm_t, perm_e, bstart, topic, nullptr, nullptr, dde1f, dde3f,
        W1, q_emb, rel, b1, W2, WBF, qWb, W2h, Rbf, N, NBKT, NREL);

    // ---- scatter round 2 ----
    kscat<2><<<2 * NBKT, 256, 0, stream>>>(
        perm_t, perm_e, bstart, topic, dde1f, dde3f, dde2f, dde4f,
        W1, q_emb, rel, b1, W2, WBF, qWb, W2h, Rbf, N, NBKT, NREL);

    // ---- node GEMM (overwrites sort scratch; outputs f16 A/B) ----
    k2b_node<<<nn, 256, 0, stream>>>(
        ent, nte, topic, dde1f, dde2f, dde3f, dde4f,
        WBF, qWb, Aw, Bw, NT, N);

    // ---- edge prediction ----
    if (srt) {
        edge_pred_srt<<<(E + 15) / 16, 256, 0, stream>>>(
            perm_e, Aw, Bw, Rbf, W2h, b2, (float*)d_out, E);
    } else {
        edge_pred_f16<<<(E + 15) / 16, 256, 0, stream>>>(
            h_id, r_id, t_id, Aw, Bw, Rbf, W2h, b2, (float*)d_out, E);
    }
}